// Round 1
// baseline (553.891 us; speedup 1.0000x reference)
//
#include <hip/hip_runtime.h>

typedef short bf16x8_t __attribute__((ext_vector_type(8)));
typedef float f32x4_t __attribute__((ext_vector_type(4)));

#define B_DIM 4096
#define Q_DIM 256
#define D_DIM 512
#define H_DIM 1024
#define O_DIM 512
#define E_NUM 16
#define K_TOP 4

#define BM 128
#define BN 128
#define BK 32
#define LDK 56  // LDS row stride (bf16 elems): 112B -> 16B-aligned rows, bank-balanced

__device__ __forceinline__ short f2bf(float f) {
  unsigned int u = __float_as_uint(f);
  u += 0x7FFFu + ((u >> 16) & 1u);  // round-to-nearest-even
  return (short)(u >> 16);
}

// ---------------- transpose + fp32->bf16 convert: src [E][R][C] f32 -> dst [E][C][R] bf16
__global__ __launch_bounds__(256) void transpose_cvt(const float* __restrict__ src,
                                                     short* __restrict__ dst, int R, int C) {
  __shared__ float tile[64][65];
  const int e = blockIdx.z;
  const int r0 = blockIdx.y * 64, c0 = blockIdx.x * 64;
  const int t = threadIdx.x;
  const float* s = src + (size_t)e * R * C;
  short* d = dst + (size_t)e * R * C;
#pragma unroll
  for (int i = 0; i < 16; i++) {
    int lin = i * 256 + t;
    int rr = lin >> 6, cc = lin & 63;
    tile[rr][cc] = s[(size_t)(r0 + rr) * C + (c0 + cc)];
  }
  __syncthreads();
#pragma unroll
  for (int i = 0; i < 16; i++) {
    int lin = i * 256 + t;
    int cr = lin >> 6, rc = lin & 63;
    d[(size_t)(c0 + cr) * R + (r0 + rc)] = f2bf(tile[rc][cr]);
  }
}

// ---------------- gating: logits (fp64 accum), top-4, softmax, CSR lists, importance/load
__global__ __launch_bounds__(64) void gating_kernel(
    const float* __restrict__ x, const float* __restrict__ query,
    const float* __restrict__ wg, const float* __restrict__ tg,
    int* __restrict__ count, float* __restrict__ importance, float* __restrict__ loadv,
    int* __restrict__ rowlist, int* __restrict__ slotid, float* __restrict__ egate) {
  const int b = blockIdx.x;
  const int lane = threadIdx.x;
  const int e = lane & 15, c = lane >> 4;
  const float* xr = x + (size_t)b * D_DIM;
  const float* qr = query + (size_t)b * Q_DIM;
  double acc = 0.0;
  for (int d = c * 128; d < c * 128 + 128; d++)
    acc += (double)xr[d] * (double)wg[d * E_NUM + e];
  for (int qq = c * 64; qq < c * 64 + 64; qq++)
    acc += (double)qr[qq] * (double)tg[qq * E_NUM + e];
  acc += __shfl_xor(acc, 16, 64);
  acc += __shfl_xor(acc, 32, 64);
  __shared__ float lg[E_NUM];
  if (lane < E_NUM) lg[lane] = (float)acc;
  __syncthreads();
  if (lane == 0) {
    float v[E_NUM];
#pragma unroll
    for (int i = 0; i < E_NUM; i++) v[i] = lg[i];
    int idx[K_TOP];
    float val[K_TOP];
    unsigned used = 0;
    for (int s = 0; s < K_TOP; s++) {  // strict '>' => lowest index wins ties (top_k order)
      float best = -3.4e38f;
      int bi = 0;
      for (int i = 0; i < E_NUM; i++)
        if (!(used & (1u << i)) && v[i] > best) { best = v[i]; bi = i; }
      used |= 1u << bi;
      idx[s] = bi;
      val[s] = best;
    }
    float mx = val[0];
    float ex[K_TOP], Z = 0.f;
    for (int s = 0; s < K_TOP; s++) { ex[s] = expf(val[s] - mx); Z += ex[s]; }
    for (int s = 0; s < K_TOP; s++) {
      float g = ex[s] / Z;
      int ee = idx[s];
      int pos = atomicAdd(&count[ee], 1);
      rowlist[ee * B_DIM + pos] = b;
      slotid[ee * B_DIM + pos] = b * K_TOP + s;
      egate[ee * B_DIM + pos] = g;
      atomicAdd(&importance[ee], g);
      atomicAdd(&loadv[ee], 1.0f);
    }
  }
}

// ---------------- loss (cv^2 ddof=1) + per-expert prefix offsets
__global__ void loss_offsets_kernel(const int* __restrict__ count,
                                    const float* __restrict__ importance,
                                    const float* __restrict__ loadv,
                                    int* __restrict__ offs, float* __restrict__ out_loss) {
  if (threadIdx.x == 0) {
    float mi = 0.f, ml = 0.f;
    for (int i = 0; i < E_NUM; i++) { mi += importance[i]; ml += loadv[i]; }
    mi /= (float)E_NUM;
    ml /= (float)E_NUM;
    float vi = 0.f, vl = 0.f;
    for (int i = 0; i < E_NUM; i++) {
      float di = importance[i] - mi;
      vi += di * di;
      float dl = loadv[i] - ml;
      vl += dl * dl;
    }
    vi /= (float)(E_NUM - 1);
    vl /= (float)(E_NUM - 1);
    out_loss[0] = 0.01f * (vi / (mi * mi + 1e-10f) + vl / (ml * ml + 1e-10f));
    int run = 0;
    for (int i = 0; i < E_NUM; i++) { offs[i] = run; run += count[i]; }
  }
}

// ---------------- GEMM1: h[entry] = relu(x[row] @ W1[e] + b1[e]), bf16 out
__global__ __launch_bounds__(256) void gemm1_kernel(
    const float* __restrict__ x, const short* __restrict__ w1t,
    const float* __restrict__ b1, const int* __restrict__ count,
    const int* __restrict__ offs, const int* __restrict__ rowlist,
    short* __restrict__ h_buf) {
  const int e = blockIdx.z, mt = blockIdx.y, nt = blockIdx.x;
  const int n_e = count[e];
  if (mt * BM >= n_e) return;
  __shared__ __align__(16) short As[BM * LDK];
  __shared__ __align__(16) short Bs[BN * LDK];
  const int t = threadIdx.x;
  const int lane = t & 63, wave = t >> 6;
  const int wm = wave >> 1, wn = wave & 1;
  const int r_row = t >> 2, q = t & 3;

  const int m0 = mt * BM + r_row, m1 = m0 + 64;
  const int xrow0 = rowlist[e * B_DIM + (m0 < n_e ? m0 : 0)];
  const int xrow1 = rowlist[e * B_DIM + (m1 < n_e ? m1 : 0)];
  const short* w1te = w1t + ((size_t)e * H_DIM + nt * BN) * D_DIM;

  f32x4_t acc[4][4] = {};

  for (int k0 = 0; k0 < D_DIM; k0 += BK) {
    {  // stage A (gathered fp32 x rows -> bf16 LDS)
      const float* s0 = x + (size_t)xrow0 * D_DIM + k0 + q * 8;
      float4 f0 = *(const float4*)s0;
      float4 f1 = *(const float4*)(s0 + 4);
      bf16x8_t v;
      v[0] = f2bf(f0.x); v[1] = f2bf(f0.y); v[2] = f2bf(f0.z); v[3] = f2bf(f0.w);
      v[4] = f2bf(f1.x); v[5] = f2bf(f1.y); v[6] = f2bf(f1.z); v[7] = f2bf(f1.w);
      *(bf16x8_t*)&As[r_row * LDK + q * 8] = v;
      const float* s1 = x + (size_t)xrow1 * D_DIM + k0 + q * 8;
      f0 = *(const float4*)s1;
      f1 = *(const float4*)(s1 + 4);
      v[0] = f2bf(f0.x); v[1] = f2bf(f0.y); v[2] = f2bf(f0.z); v[3] = f2bf(f0.w);
      v[4] = f2bf(f1.x); v[5] = f2bf(f1.y); v[6] = f2bf(f1.z); v[7] = f2bf(f1.w);
      *(bf16x8_t*)&As[(64 + r_row) * LDK + q * 8] = v;
    }
    {  // stage B (bf16 W1T rows, contiguous)
      *(bf16x8_t*)&Bs[r_row * LDK + q * 8] =
          *(const bf16x8_t*)(w1te + (size_t)r_row * D_DIM + k0 + q * 8);
      *(bf16x8_t*)&Bs[(64 + r_row) * LDK + q * 8] =
          *(const bf16x8_t*)(w1te + (size_t)(64 + r_row) * D_DIM + k0 + q * 8);
    }
    __syncthreads();
    bf16x8_t af[4], bfr[4];
#pragma unroll
    for (int mi = 0; mi < 4; mi++)
      af[mi] = *(const bf16x8_t*)&As[(wm * 64 + mi * 16 + (lane & 15)) * LDK + 8 * (lane >> 4)];
#pragma unroll
    for (int ni = 0; ni < 4; ni++)
      bfr[ni] = *(const bf16x8_t*)&Bs[(wn * 64 + ni * 16 + (lane & 15)) * LDK + 8 * (lane >> 4)];
#pragma unroll
    for (int mi = 0; mi < 4; mi++)
#pragma unroll
      for (int ni = 0; ni < 4; ni++)
        acc[mi][ni] = __builtin_amdgcn_mfma_f32_16x16x32_bf16(af[mi], bfr[ni], acc[mi][ni], 0, 0, 0);
    __syncthreads();
  }
  const int col_l = lane & 15, rq = lane >> 4;
  const int obase = offs[e];
#pragma unroll
  for (int mi = 0; mi < 4; mi++) {
#pragma unroll
    for (int r = 0; r < 4; r++) {
      int row = wm * 64 + mi * 16 + rq * 4 + r;
      int m_local = mt * BM + row;
      if (m_local >= n_e) continue;
      size_t hrow = (size_t)(obase + m_local) * H_DIM;
#pragma unroll
      for (int ni = 0; ni < 4; ni++) {
        int col = nt * BN + wn * 64 + ni * 16 + col_l;
        float v = acc[mi][ni][r] + b1[e * H_DIM + col];
        h_buf[hrow + col] = f2bf(v > 0.f ? v : 0.f);
      }
    }
  }
}

// ---------------- GEMM2: out[slot] = (h[entry] @ W2[e] + b2[e]) * gate, fp32 scatter
__global__ __launch_bounds__(256) void gemm2_kernel(
    const short* __restrict__ h_buf, const short* __restrict__ w2t,
    const float* __restrict__ b2, const int* __restrict__ count,
    const int* __restrict__ offs, const int* __restrict__ slotid,
    const float* __restrict__ egate, float* __restrict__ out_buf) {
  const int e = blockIdx.z, mt = blockIdx.y, nt = blockIdx.x;
  const int n_e = count[e];
  if (mt * BM >= n_e) return;
  __shared__ __align__(16) short As[BM * LDK];
  __shared__ __align__(16) short Bs[BN * LDK];
  const int t = threadIdx.x;
  const int lane = t & 63, wave = t >> 6;
  const int wm = wave >> 1, wn = wave & 1;
  const int r_row = t >> 2, q = t & 3;
  const int obase = offs[e];
  const int m0 = mt * BM + r_row, m1 = m0 + 64;
  const size_t ar0 = (size_t)(obase + (m0 < n_e ? m0 : n_e - 1)) * H_DIM;
  const size_t ar1 = (size_t)(obase + (m1 < n_e ? m1 : n_e - 1)) * H_DIM;
  const short* w2te = w2t + ((size_t)e * O_DIM + nt * BN) * H_DIM;

  f32x4_t acc[4][4] = {};

  for (int k0 = 0; k0 < H_DIM; k0 += BK) {
    *(bf16x8_t*)&As[r_row * LDK + q * 8] = *(const bf16x8_t*)(h_buf + ar0 + k0 + q * 8);
    *(bf16x8_t*)&As[(64 + r_row) * LDK + q * 8] = *(const bf16x8_t*)(h_buf + ar1 + k0 + q * 8);
    *(bf16x8_t*)&Bs[r_row * LDK + q * 8] =
        *(const bf16x8_t*)(w2te + (size_t)r_row * H_DIM + k0 + q * 8);
    *(bf16x8_t*)&Bs[(64 + r_row) * LDK + q * 8] =
        *(const bf16x8_t*)(w2te + (size_t)(64 + r_row) * H_DIM + k0 + q * 8);
    __syncthreads();
    bf16x8_t af[4], bfr[4];
#pragma unroll
    for (int mi = 0; mi < 4; mi++)
      af[mi] = *(const bf16x8_t*)&As[(wm * 64 + mi * 16 + (lane & 15)) * LDK + 8 * (lane >> 4)];
#pragma unroll
    for (int ni = 0; ni < 4; ni++)
      bfr[ni] = *(const bf16x8_t*)&Bs[(wn * 64 + ni * 16 + (lane & 15)) * LDK + 8 * (lane >> 4)];
#pragma unroll
    for (int mi = 0; mi < 4; mi++)
#pragma unroll
      for (int ni = 0; ni < 4; ni++)
        acc[mi][ni] = __builtin_amdgcn_mfma_f32_16x16x32_bf16(af[mi], bfr[ni], acc[mi][ni], 0, 0, 0);
    __syncthreads();
  }
  const int col_l = lane & 15, rq = lane >> 4;
#pragma unroll
  for (int mi = 0; mi < 4; mi++) {
#pragma unroll
    for (int r = 0; r < 4; r++) {
      int row = wm * 64 + mi * 16 + rq * 4 + r;
      int m_local = mt * BM + row;
      if (m_local >= n_e) continue;
      float g = egate[e * B_DIM + m_local];
      size_t orow = (size_t)slotid[e * B_DIM + m_local] * O_DIM;
#pragma unroll
      for (int ni = 0; ni < 4; ni++) {
        int col = nt * BN + wn * 64 + ni * 16 + col_l;
        out_buf[orow + col] = (acc[mi][ni][r] + b2[e * O_DIM + col]) * g;
      }
    }
  }
}

// ---------------- combine: y[b] = sum over 4 slots
__global__ __launch_bounds__(256) void combine_kernel(const float* __restrict__ out_buf,
                                                      float* __restrict__ y) {
  int idx = blockIdx.x * 256 + threadIdx.x;  // B*O/4 threads
  int b = idx >> 7;
  int o = (idx & 127) << 2;
  const float* base = out_buf + (size_t)b * K_TOP * O_DIM + o;
  float4 a0 = *(const float4*)(base);
  float4 a1 = *(const float4*)(base + O_DIM);
  float4 a2 = *(const float4*)(base + 2 * O_DIM);
  float4 a3 = *(const float4*)(base + 3 * O_DIM);
  float4 r;
  r.x = a0.x + a1.x + a2.x + a3.x;
  r.y = a0.y + a1.y + a2.y + a3.y;
  r.z = a0.z + a1.z + a2.z + a3.z;
  r.w = a0.w + a1.w + a2.w + a3.w;
  *(float4*)(y + (size_t)b * O_DIM + o) = r;
}

extern "C" void kernel_launch(void* const* d_in, const int* in_sizes, int n_in,
                              void* d_out, int out_size, void* d_ws, size_t ws_size,
                              hipStream_t stream) {
  (void)in_sizes; (void)n_in; (void)out_size; (void)ws_size;
  const float* query = (const float*)d_in[0];
  const float* x = (const float*)d_in[1];
  const float* wg = (const float*)d_in[2];
  const float* tg = (const float*)d_in[3];
  const float* W1 = (const float*)d_in[4];
  const float* b1 = (const float*)d_in[5];
  const float* W2 = (const float*)d_in[6];
  const float* b2 = (const float*)d_in[7];
  float* y = (float*)d_out;

  char* ws = (char*)d_ws;
  int* count = (int*)(ws + 0);          // 64 B
  float* imp = (float*)(ws + 64);       // 64 B
  float* loadv = (float*)(ws + 128);    // 64 B
  int* offs = (int*)(ws + 192);         // 64 B
  int* rowlist = (int*)(ws + 256);      // 16*4096*4 = 256 KB
  int* slotid = (int*)(ws + 262400);    // 256 KB
  float* egate = (float*)(ws + 524544); // 256 KB
  short* w1t = (short*)(ws + 786688);   // 16 MB bf16 [E][H][D]
  short* w2t = (short*)(ws + 17563904); // 16 MB bf16 [E][O][H]
  short* h_buf = (short*)(ws + 34341120);   // 32 MB bf16 [16384][H]
  float* out_buf = (float*)(ws + 67895552); // 32 MB f32 [16384][O]

  hipMemsetAsync(ws, 0, 192, stream);
  transpose_cvt<<<dim3(H_DIM / 64, D_DIM / 64, E_NUM), 256, 0, stream>>>(W1, w1t, D_DIM, H_DIM);
  transpose_cvt<<<dim3(O_DIM / 64, H_DIM / 64, E_NUM), 256, 0, stream>>>(W2, w2t, H_DIM, O_DIM);
  gating_kernel<<<dim3(B_DIM), 64, 0, stream>>>(x, query, wg, tg, count, imp, loadv,
                                                rowlist, slotid, egate);
  loss_offsets_kernel<<<1, 64, 0, stream>>>(count, imp, loadv, offs,
                                            y + (size_t)B_DIM * O_DIM);
  gemm1_kernel<<<dim3(H_DIM / BN, B_DIM / BM, E_NUM), 256, 0, stream>>>(
      x, w1t, b1, count, offs, rowlist, h_buf);
  gemm2_kernel<<<dim3(O_DIM / BN, B_DIM / BM, E_NUM), 256, 0, stream>>>(
      h_buf, w2t, b2, count, offs, slotid, egate, out_buf);
  combine_kernel<<<dim3(B_DIM * O_DIM / 4 / 256), 256, 0, stream>>>(out_buf, y);
}

// Round 2
// 312.602 us; speedup vs baseline: 1.7719x; 1.7719x over previous
//
#include <hip/hip_runtime.h>

typedef short bf16x8_t __attribute__((ext_vector_type(8)));
typedef float f32x4_t __attribute__((ext_vector_type(4)));

#define B_DIM 4096
#define Q_DIM 256
#define D_DIM 512
#define H_DIM 1024
#define O_DIM 512
#define E_NUM 16
#define K_TOP 4

#define BM 128
#define BN 128
#define BK 32
#define LDK 56  // LDS row stride (bf16 elems): 112B -> 16B-aligned rows, bank-balanced

// gating LDS strides (floats): ===4 mod 32 (2-way bank alias = free), *4B multiple of 16
#define WG_LD 548
#define TG_LD 292

__device__ __forceinline__ short f2bf(float f) {
  unsigned int u = __float_as_uint(f);
  u += 0x7FFFu + ((u >> 16) & 1u);  // round-to-nearest-even
  return (short)(u >> 16);
}

// ---------------- transpose + fp32->bf16 convert: src [E][R][C] f32 -> dst [E][C][R] bf16
__global__ __launch_bounds__(256) void transpose_cvt(const float* __restrict__ src,
                                                     short* __restrict__ dst, int R, int C) {
  __shared__ float tile[64][65];
  const int e = blockIdx.z;
  const int r0 = blockIdx.y * 64, c0 = blockIdx.x * 64;
  const int t = threadIdx.x;
  const float* s = src + (size_t)e * R * C;
  short* d = dst + (size_t)e * R * C;
#pragma unroll
  for (int i = 0; i < 16; i++) {
    int lin = i * 256 + t;
    int rr = lin >> 6, cc = lin & 63;
    tile[rr][cc] = s[(size_t)(r0 + rr) * C + (c0 + cc)];
  }
  __syncthreads();
#pragma unroll
  for (int i = 0; i < 16; i++) {
    int lin = i * 256 + t;
    int cr = lin >> 6, rc = lin & 63;
    d[(size_t)(c0 + cr) * R + (r0 + rc)] = f2bf(tile[rc][cr]);
  }
}

// ---------------- gating: 16 rows/block, 1 thread per (row, expert).
// fp64-exact products (same as the R1-passing kernel, so top-k decisions are stable),
// LDS-staged transposed gate weights for ds_read_b128.
__global__ __launch_bounds__(256) void gating_kernel(
    const float* __restrict__ x, const float* __restrict__ query,
    const float* __restrict__ wg, const float* __restrict__ tg,
    int* __restrict__ count,
    int* __restrict__ rowlist, int* __restrict__ slotid, float* __restrict__ egate) {
  __shared__ __align__(16) float s_wg[E_NUM * WG_LD];
  __shared__ __align__(16) float s_tg[E_NUM * TG_LD];
  __shared__ float s_lg[16][E_NUM];
  const int t = threadIdx.x;
  const int blk = blockIdx.x;

  // stage w_gate [512][16] -> s_wg[e][d] (transposed)
#pragma unroll
  for (int i = 0; i < 8; i++) {
    int idx4 = (i * 256 + t) * 4;           // covers 8192 floats
    float4 v = *(const float4*)(wg + idx4); // 4 consecutive e, same d
    int d = idx4 >> 4, e0 = idx4 & 15;
    s_wg[(e0 + 0) * WG_LD + d] = v.x;
    s_wg[(e0 + 1) * WG_LD + d] = v.y;
    s_wg[(e0 + 2) * WG_LD + d] = v.z;
    s_wg[(e0 + 3) * WG_LD + d] = v.w;
  }
  // stage task_gate [256][16] -> s_tg[e][q]
#pragma unroll
  for (int i = 0; i < 4; i++) {
    int idx4 = (i * 256 + t) * 4;           // covers 4096 floats
    float4 v = *(const float4*)(tg + idx4);
    int q = idx4 >> 4, e0 = idx4 & 15;
    s_tg[(e0 + 0) * TG_LD + q] = v.x;
    s_tg[(e0 + 1) * TG_LD + q] = v.y;
    s_tg[(e0 + 2) * TG_LD + q] = v.z;
    s_tg[(e0 + 3) * TG_LD + q] = v.w;
  }
  __syncthreads();

  const int row_l = t >> 4, e = t & 15;
  const int row = blk * 16 + row_l;
  const float* xr = x + (size_t)row * D_DIM;
  const float* qr = query + (size_t)row * Q_DIM;
  const float* wge = s_wg + e * WG_LD;
  const float* tge = s_tg + e * TG_LD;
  double a0 = 0, a1 = 0, a2 = 0, a3 = 0;
#pragma unroll 4
  for (int d = 0; d < D_DIM; d += 4) {
    float4 xv = *(const float4*)(xr + d);
    float4 wv = *(const float4*)(wge + d);
    a0 += (double)xv.x * (double)wv.x;
    a1 += (double)xv.y * (double)wv.y;
    a2 += (double)xv.z * (double)wv.z;
    a3 += (double)xv.w * (double)wv.w;
  }
#pragma unroll 4
  for (int q = 0; q < Q_DIM; q += 4) {
    float4 xv = *(const float4*)(qr + q);
    float4 wv = *(const float4*)(tge + q);
    a0 += (double)xv.x * (double)wv.x;
    a1 += (double)xv.y * (double)wv.y;
    a2 += (double)xv.z * (double)wv.z;
    a3 += (double)xv.w * (double)wv.w;
  }
  s_lg[row_l][e] = (float)((a0 + a2) + (a1 + a3));
  __syncthreads();

  if (t < 16) {
    const int b = blk * 16 + t;
    float v[E_NUM];
#pragma unroll
    for (int i = 0; i < E_NUM; i++) v[i] = s_lg[t][i];
    int idx[K_TOP];
    float val[K_TOP];
    unsigned used = 0;
    for (int s = 0; s < K_TOP; s++) {  // strict '>' => lowest index wins ties (top_k order)
      float best = -3.4e38f;
      int bi = 0;
      for (int i = 0; i < E_NUM; i++)
        if (!(used & (1u << i)) && v[i] > best) { best = v[i]; bi = i; }
      used |= 1u << bi;
      idx[s] = bi;
      val[s] = best;
    }
    float mx = val[0];
    float ex[K_TOP], Z = 0.f;
    for (int s = 0; s < K_TOP; s++) { ex[s] = __expf(val[s] - mx); Z += ex[s]; }
    for (int s = 0; s < K_TOP; s++) {
      float g = ex[s] / Z;
      int ee = idx[s];
      int pos = atomicAdd(&count[ee], 1);
      rowlist[ee * B_DIM + pos] = b;
      slotid[ee * B_DIM + pos] = b * K_TOP + s;
      egate[ee * B_DIM + pos] = g;
    }
  }
}

// ---------------- loss (cv^2 ddof=1, importance from egate lists, load==count) + offsets
__global__ __launch_bounds__(256) void loss_offsets_kernel(
    const int* __restrict__ count, const float* __restrict__ egate,
    int* __restrict__ offs, float* __restrict__ out_loss) {
  __shared__ float s_imp[E_NUM];
  const int t = threadIdx.x;
  if (t < E_NUM) s_imp[t] = 0.f;
  __syncthreads();
  for (int e = 0; e < E_NUM; e++) {
    int n = count[e];
    float p = 0.f;
    for (int i = t; i < n; i += 256) p += egate[e * B_DIM + i];
    // wave-level reduce then one LDS atomic per wave
    for (int off = 32; off >= 1; off >>= 1) p += __shfl_down(p, off, 64);
    if ((t & 63) == 0) atomicAdd(&s_imp[e], p);
  }
  __syncthreads();
  if (t == 0) {
    float mi = 0.f, ml = 0.f;
    for (int i = 0; i < E_NUM; i++) { mi += s_imp[i]; ml += (float)count[i]; }
    mi /= (float)E_NUM;
    ml /= (float)E_NUM;
    float vi = 0.f, vl = 0.f;
    for (int i = 0; i < E_NUM; i++) {
      float di = s_imp[i] - mi;
      vi += di * di;
      float dl = (float)count[i] - ml;
      vl += dl * dl;
    }
    vi /= (float)(E_NUM - 1);
    vl /= (float)(E_NUM - 1);
    out_loss[0] = 0.01f * (vi / (mi * mi + 1e-10f) + vl / (ml * ml + 1e-10f));
    int run = 0;
    for (int i = 0; i < E_NUM; i++) { offs[i] = run; run += count[i]; }
  }
}

// ---------------- GEMM1: h[entry] = relu(x[row] @ W1[e] + b1[e]), bf16 out
__global__ __launch_bounds__(256) void gemm1_kernel(
    const float* __restrict__ x, const short* __restrict__ w1t,
    const float* __restrict__ b1, const int* __restrict__ count,
    const int* __restrict__ offs, const int* __restrict__ rowlist,
    short* __restrict__ h_buf) {
  const int e = blockIdx.z, mt = blockIdx.y, nt = blockIdx.x;
  const int n_e = count[e];
  if (mt * BM >= n_e) return;
  __shared__ __align__(16) short As[BM * LDK];
  __shared__ __align__(16) short Bs[BN * LDK];
  const int t = threadIdx.x;
  const int lane = t & 63, wave = t >> 6;
  const int wm = wave >> 1, wn = wave & 1;
  const int r_row = t >> 2, q = t & 3;

  const int m0 = mt * BM + r_row, m1 = m0 + 64;
  const int xrow0 = rowlist[e * B_DIM + (m0 < n_e ? m0 : 0)];
  const int xrow1 = rowlist[e * B_DIM + (m1 < n_e ? m1 : 0)];
  const short* w1te = w1t + ((size_t)e * H_DIM + nt * BN) * D_DIM;

  f32x4_t acc[4][4] = {};

  for (int k0 = 0; k0 < D_DIM; k0 += BK) {
    {  // stage A (gathered fp32 x rows -> bf16 LDS)
      const float* s0 = x + (size_t)xrow0 * D_DIM + k0 + q * 8;
      float4 f0 = *(const float4*)s0;
      float4 f1 = *(const float4*)(s0 + 4);
      bf16x8_t v;
      v[0] = f2bf(f0.x); v[1] = f2bf(f0.y); v[2] = f2bf(f0.z); v[3] = f2bf(f0.w);
      v[4] = f2bf(f1.x); v[5] = f2bf(f1.y); v[6] = f2bf(f1.z); v[7] = f2bf(f1.w);
      *(bf16x8_t*)&As[r_row * LDK + q * 8] = v;
      const float* s1 = x + (size_t)xrow1 * D_DIM + k0 + q * 8;
      f0 = *(const float4*)s1;
      f1 = *(const float4*)(s1 + 4);
      v[0] = f2bf(f0.x); v[1] = f2bf(f0.y); v[2] = f2bf(f0.z); v[3] = f2bf(f0.w);
      v[4] = f2bf(f1.x); v[5] = f2bf(f1.y); v[6] = f2bf(f1.z); v[7] = f2bf(f1.w);
      *(bf16x8_t*)&As[(64 + r_row) * LDK + q * 8] = v;
    }
    {  // stage B (bf16 W1T rows, contiguous)
      *(bf16x8_t*)&Bs[r_row * LDK + q * 8] =
          *(const bf16x8_t*)(w1te + (size_t)r_row * D_DIM + k0 + q * 8);
      *(bf16x8_t*)&Bs[(64 + r_row) * LDK + q * 8] =
          *(const bf16x8_t*)(w1te + (size_t)(64 + r_row) * D_DIM + k0 + q * 8);
    }
    __syncthreads();
    bf16x8_t af[4], bfr[4];
#pragma unroll
    for (int mi = 0; mi < 4; mi++)
      af[mi] = *(const bf16x8_t*)&As[(wm * 64 + mi * 16 + (lane & 15)) * LDK + 8 * (lane >> 4)];
#pragma unroll
    for (int ni = 0; ni < 4; ni++)
      bfr[ni] = *(const bf16x8_t*)&Bs[(wn * 64 + ni * 16 + (lane & 15)) * LDK + 8 * (lane >> 4)];
#pragma unroll
    for (int mi = 0; mi < 4; mi++)
#pragma unroll
      for (int ni = 0; ni < 4; ni++)
        acc[mi][ni] = __builtin_amdgcn_mfma_f32_16x16x32_bf16(af[mi], bfr[ni], acc[mi][ni], 0, 0, 0);
    __syncthreads();
  }
  const int col_l = lane & 15, rq = lane >> 4;
  const int obase = offs[e];
#pragma unroll
  for (int mi = 0; mi < 4; mi++) {
#pragma unroll
    for (int r = 0; r < 4; r++) {
      int row = wm * 64 + mi * 16 + rq * 4 + r;
      int m_local = mt * BM + row;
      if (m_local >= n_e) continue;
      size_t hrow = (size_t)(obase + m_local) * H_DIM;
#pragma unroll
      for (int ni = 0; ni < 4; ni++) {
        int col = nt * BN + wn * 64 + ni * 16 + col_l;
        float v = acc[mi][ni][r] + b1[e * H_DIM + col];
        h_buf[hrow + col] = f2bf(v > 0.f ? v : 0.f);
      }
    }
  }
}

// ---------------- GEMM2: out[slot] = (h[entry] @ W2[e] + b2[e]) * gate, fp32 scatter
__global__ __launch_bounds__(256) void gemm2_kernel(
    const short* __restrict__ h_buf, const short* __restrict__ w2t,
    const float* __restrict__ b2, const int* __restrict__ count,
    const int* __restrict__ offs, const int* __restrict__ slotid,
    const float* __restrict__ egate, float* __restrict__ out_buf) {
  const int e = blockIdx.z, mt = blockIdx.y, nt = blockIdx.x;
  const int n_e = count[e];
  if (mt * BM >= n_e) return;
  __shared__ __align__(16) short As[BM * LDK];
  __shared__ __align__(16) short Bs[BN * LDK];
  const int t = threadIdx.x;
  const int lane = t & 63, wave = t >> 6;
  const int wm = wave >> 1, wn = wave & 1;
  const int r_row = t >> 2, q = t & 3;
  const int obase = offs[e];
  const int m0 = mt * BM + r_row, m1 = m0 + 64;
  const size_t ar0 = (size_t)(obase + (m0 < n_e ? m0 : n_e - 1)) * H_DIM;
  const size_t ar1 = (size_t)(obase + (m1 < n_e ? m1 : n_e - 1)) * H_DIM;
  const short* w2te = w2t + ((size_t)e * O_DIM + nt * BN) * H_DIM;

  f32x4_t acc[4][4] = {};

  for (int k0 = 0; k0 < H_DIM; k0 += BK) {
    *(bf16x8_t*)&As[r_row * LDK + q * 8] = *(const bf16x8_t*)(h_buf + ar0 + k0 + q * 8);
    *(bf16x8_t*)&As[(64 + r_row) * LDK + q * 8] = *(const bf16x8_t*)(h_buf + ar1 + k0 + q * 8);
    *(bf16x8_t*)&Bs[r_row * LDK + q * 8] =
        *(const bf16x8_t*)(w2te + (size_t)r_row * H_DIM + k0 + q * 8);
    *(bf16x8_t*)&Bs[(64 + r_row) * LDK + q * 8] =
        *(const bf16x8_t*)(w2te + (size_t)(64 + r_row) * H_DIM + k0 + q * 8);
    __syncthreads();
    bf16x8_t af[4], bfr[4];
#pragma unroll
    for (int mi = 0; mi < 4; mi++)
      af[mi] = *(const bf16x8_t*)&As[(wm * 64 + mi * 16 + (lane & 15)) * LDK + 8 * (lane >> 4)];
#pragma unroll
    for (int ni = 0; ni < 4; ni++)
      bfr[ni] = *(const bf16x8_t*)&Bs[(wn * 64 + ni * 16 + (lane & 15)) * LDK + 8 * (lane >> 4)];
#pragma unroll
    for (int mi = 0; mi < 4; mi++)
#pragma unroll
      for (int ni = 0; ni < 4; ni++)
        acc[mi][ni] = __builtin_amdgcn_mfma_f32_16x16x32_bf16(af[mi], bfr[ni], acc[mi][ni], 0, 0, 0);
    __syncthreads();
  }
  const int col_l = lane & 15, rq = lane >> 4;
#pragma unroll
  for (int mi = 0; mi < 4; mi++) {
#pragma unroll
    for (int r = 0; r < 4; r++) {
      int row = wm * 64 + mi * 16 + rq * 4 + r;
      int m_local = mt * BM + row;
      if (m_local >= n_e) continue;
      float g = egate[e * B_DIM + m_local];
      size_t orow = (size_t)slotid[e * B_DIM + m_local] * O_DIM;
#pragma unroll
      for (int ni = 0; ni < 4; ni++) {
        int col = nt * BN + wn * 64 + ni * 16 + col_l;
        out_buf[orow + col] = (acc[mi][ni][r] + b2[e * O_DIM + col]) * g;
      }
    }
  }
}

// ---------------- combine: y[b] = sum over 4 slots
__global__ __launch_bounds__(256) void combine_kernel(const float* __restrict__ out_buf,
                                                      float* __restrict__ y) {
  int idx = blockIdx.x * 256 + threadIdx.x;  // B*O/4 threads
  int b = idx >> 7;
  int o = (idx & 127) << 2;
  const float* base = out_buf + (size_t)b * K_TOP * O_DIM + o;
  float4 a0 = *(const float4*)(base);
  float4 a1 = *(const float4*)(base + O_DIM);
  float4 a2 = *(const float4*)(base + 2 * O_DIM);
  float4 a3 = *(const float4*)(base + 3 * O_DIM);
  float4 r;
  r.x = a0.x + a1.x + a2.x + a3.x;
  r.y = a0.y + a1.y + a2.y + a3.y;
  r.z = a0.z + a1.z + a2.z + a3.z;
  r.w = a0.w + a1.w + a2.w + a3.w;
  *(float4*)(y + (size_t)b * O_DIM + o) = r;
}

extern "C" void kernel_launch(void* const* d_in, const int* in_sizes, int n_in,
                              void* d_out, int out_size, void* d_ws, size_t ws_size,
                              hipStream_t stream) {
  (void)in_sizes; (void)n_in; (void)out_size; (void)ws_size;
  const float* query = (const float*)d_in[0];
  const float* x = (const float*)d_in[1];
  const float* wg = (const float*)d_in[2];
  const float* tg = (const float*)d_in[3];
  const float* W1 = (const float*)d_in[4];
  const float* b1 = (const float*)d_in[5];
  const float* W2 = (const float*)d_in[6];
  const float* b2 = (const float*)d_in[7];
  float* y = (float*)d_out;

  char* ws = (char*)d_ws;
  int* count = (int*)(ws + 0);          // 64 B
  int* offs = (int*)(ws + 192);         // 64 B
  int* rowlist = (int*)(ws + 256);      // 16*4096*4 = 256 KB
  int* slotid = (int*)(ws + 262400);    // 256 KB
  float* egate = (float*)(ws + 524544); // 256 KB
  short* w1t = (short*)(ws + 786688);   // 16 MB bf16 [E][H][D]
  short* w2t = (short*)(ws + 17563904); // 16 MB bf16 [E][O][H]
  short* h_buf = (short*)(ws + 34341120);   // 32 MB bf16 [16384][H]
  float* out_buf = (float*)(ws + 67895552); // 32 MB f32 [16384][O]

  hipMemsetAsync(ws, 0, 192, stream);
  transpose_cvt<<<dim3(H_DIM / 64, D_DIM / 64, E_NUM), 256, 0, stream>>>(W1, w1t, D_DIM, H_DIM);
  transpose_cvt<<<dim3(O_DIM / 64, H_DIM / 64, E_NUM), 256, 0, stream>>>(W2, w2t, H_DIM, O_DIM);
  gating_kernel<<<dim3(B_DIM / 16), 256, 0, stream>>>(x, query, wg, tg, count,
                                                      rowlist, slotid, egate);
  loss_offsets_kernel<<<1, 256, 0, stream>>>(count, egate, offs,
                                             y + (size_t)B_DIM * O_DIM);
  gemm1_kernel<<<dim3(H_DIM / BN, B_DIM / BM, E_NUM), 256, 0, stream>>>(
      x, w1t, b1, count, offs, rowlist, h_buf);
  gemm2_kernel<<<dim3(O_DIM / BN, B_DIM / BM, E_NUM), 256, 0, stream>>>(
      h_buf, w2t, b2, count, offs, slotid, egate, out_buf);
  combine_kernel<<<dim3(B_DIM * O_DIM / 4 / 256), 256, 0, stream>>>(out_buf, y);
}